// Round 1
// baseline (174.869 us; speedup 1.0000x reference)
//
#include <hip/hip_runtime.h>

typedef _Float16 half8 __attribute__((ext_vector_type(8)));
typedef float f32x4 __attribute__((ext_vector_type(4)));
typedef unsigned int u32x2 __attribute__((ext_vector_type(2)));

#define SELU_SCALE 1.0507009873554805f
#define SELU_ALPHA 1.6732632423543772f

// ---- LDS layout (bytes) ----
// Weight tiles stored transposed WT[f_out][k] as f16, row pitch padded:
//   K=32  -> 80 B rows (64 B data + 16 pad)  => 2-way-max bank conflicts
//   K=128 -> 272 B rows (256 B data + 16 pad)
#define WT0_OFF 0        // 32 rows x 80  (K padded 6->32 with zeros)
#define WT1_OFF 2560     // 128 rows x 80
#define WT2_OFF 12800    // 128 rows x 272
#define WT3_OFF 47616    // 32 rows x 272
#define WT4_OFF 56320    // 16 rows x 80
#define B0_OFF  57600    // f32 biases
#define B1_OFF  57728
#define B2_OFF  58240
#define B3_OFF  58752
#define B4_OFF  58880
#define W5_OFF  58944    // 16 f32 (pre-scaled)
#define B5_OFF  59008    // 1 f32
#define ACT_OFF 59024    // per-wave activation buffers: 32 rows x 272 B
#define BUF_SZ  8704
#define LDS_SZ  (ACT_OFF + 4 * 2 * BUF_SZ)   // 128656 B

__device__ __forceinline__ unsigned short f2h(float f) {
    union { _Float16 h; unsigned short u; } v;
    v.h = (_Float16)f;
    return v.u;
}

// selu with the global scale folded into the NEXT layer's weights:
// a(x) = x>0 ? x : alpha*(exp(x)-1)
__device__ __forceinline__ float act(float x) {
    float e = __expf(x);
    return x > 0.0f ? x : SELU_ALPHA * (e - 1.0f);
}

__device__ __forceinline__ f32x4 zero4() {
    f32x4 v; v[0] = 0.f; v[1] = 0.f; v[2] = 0.f; v[3] = 0.f; return v;
}

// One MFMA-tiled layer: acc[mt][nt] += WT_tile x act_tile
// A-frag: row = mt*16 + (lane&15), k = kk*32 + (lane>>4)*8 + e  (row pitch WRP bytes)
// B-frag: col(token) = nt*16 + (lane&15), same k               (row pitch 272 bytes)
template<int KIN, int FOUT, int WRP>
__device__ __forceinline__ void gemm_tile(const unsigned char* wt,
                                          const unsigned char* src,
                                          int r, int g, f32x4 (&acc)[FOUT / 16][2]) {
#pragma unroll
    for (int kk = 0; kk < KIN / 32; ++kk) {
        half8 b0 = *(const half8*)(src + r * 272 + kk * 64 + g * 16);
        half8 b1 = *(const half8*)(src + (16 + r) * 272 + kk * 64 + g * 16);
#pragma unroll
        for (int mt = 0; mt < FOUT / 16; ++mt) {
            half8 a = *(const half8*)(wt + (mt * 16 + r) * WRP + kk * 64 + g * 16);
            acc[mt][0] = __builtin_amdgcn_mfma_f32_16x16x32_f16(a, b0, acc[mt][0], 0, 0, 0);
            acc[mt][1] = __builtin_amdgcn_mfma_f32_16x16x32_f16(a, b1, acc[mt][1], 0, 0, 0);
        }
    }
}

// bias + (selu) + f16-convert + store into dst activation buffer (B-layout rows)
// D-frag: col(token) = nt*16 + (lane&15), row(feature) = mt*16 + (lane>>4)*4 + e
template<int FOUT, bool DOACT>
__device__ __forceinline__ void epilogue(unsigned char* lds, int bias_off,
                                         unsigned char* dst, int r, int g,
                                         f32x4 (&acc)[FOUT / 16][2]) {
#pragma unroll
    for (int mt = 0; mt < FOUT / 16; ++mt) {
        f32x4 bv = *(const f32x4*)(lds + bias_off + (mt * 16 + g * 4) * 4);
#pragma unroll
        for (int nt = 0; nt < 2; ++nt) {
            float v0 = acc[mt][nt][0] + bv[0];
            float v1 = acc[mt][nt][1] + bv[1];
            float v2 = acc[mt][nt][2] + bv[2];
            float v3 = acc[mt][nt][3] + bv[3];
            if (DOACT) { v0 = act(v0); v1 = act(v1); v2 = act(v2); v3 = act(v3); }
            u32x2 w;
            w[0] = (unsigned)f2h(v0) | ((unsigned)f2h(v1) << 16);
            w[1] = (unsigned)f2h(v2) | ((unsigned)f2h(v3) << 16);
            *(u32x2*)(dst + (nt * 16 + r) * 272 + (mt * 16 + g * 4) * 2) = w;
        }
    }
}

extern "C" __global__ void __launch_bounds__(256)
extractor_mlp_kernel(const float* __restrict__ x, const float* __restrict__ y,
                     const float* __restrict__ W0, const float* __restrict__ b0,
                     const float* __restrict__ W1, const float* __restrict__ b1,
                     const float* __restrict__ W2, const float* __restrict__ b2,
                     const float* __restrict__ W3, const float* __restrict__ b3,
                     const float* __restrict__ W4, const float* __restrict__ b4,
                     const float* __restrict__ W5, const float* __restrict__ b5,
                     float* __restrict__ out) {
    __shared__ __align__(16) unsigned char lds[LDS_SZ];
    const int tid = threadIdx.x;

    // ---------- stage weights into LDS (f16, transposed, padded rows) ----------
    // WT0: feature-major fill with zero pad for k>=6 (kills garbage B elems)
    for (int i = tid; i < 32 * 40; i += 256) {
        int f = i / 40, c = i % 40;
        float v = (c < 6) ? W0[c * 32 + f] : 0.0f;
        ((unsigned short*)(lds + WT0_OFF))[f * 40 + c] = f2h(v);
    }
    // WT1..WT4: k-major (coalesced reads), selu scale folded in
    for (int i = tid; i < 32 * 128; i += 256) {
        int k = i >> 7, f = i & 127;
        ((unsigned short*)(lds + WT1_OFF))[f * 40 + k] = f2h(W1[i] * SELU_SCALE);
    }
    for (int i = tid; i < 128 * 128; i += 256) {
        int k = i >> 7, f = i & 127;
        ((unsigned short*)(lds + WT2_OFF))[f * 136 + k] = f2h(W2[i] * SELU_SCALE);
    }
    for (int i = tid; i < 128 * 32; i += 256) {
        int k = i >> 5, f = i & 31;
        ((unsigned short*)(lds + WT3_OFF))[f * 136 + k] = f2h(W3[i] * SELU_SCALE);
    }
    for (int i = tid; i < 32 * 16; i += 256) {
        int k = i >> 4, f = i & 15;
        ((unsigned short*)(lds + WT4_OFF))[f * 40 + k] = f2h(W4[i] * SELU_SCALE);
    }
    for (int i = tid; i < 32; i += 256)  ((float*)(lds + B0_OFF))[i] = b0[i];
    for (int i = tid; i < 128; i += 256) ((float*)(lds + B1_OFF))[i] = b1[i];
    for (int i = tid; i < 128; i += 256) ((float*)(lds + B2_OFF))[i] = b2[i];
    for (int i = tid; i < 32; i += 256)  ((float*)(lds + B3_OFF))[i] = b3[i];
    for (int i = tid; i < 16; i += 256)  ((float*)(lds + B4_OFF))[i] = b4[i];
    for (int i = tid; i < 16; i += 256)  ((float*)(lds + W5_OFF))[i] = W5[i] * SELU_SCALE;
    if (tid == 0) *(float*)(lds + B5_OFF) = b5[0];
    __syncthreads();   // the ONLY block-wide barrier

    const int lane = tid & 63;
    const int wave = tid >> 6;
    const int r = lane & 15;   // token-within-tile / A-row lane
    const int g = lane >> 4;   // k-chunk group
    unsigned char* bufA = lds + ACT_OFF + wave * (2 * BUF_SZ);
    unsigned char* bufB = bufA + BUF_SZ;

    const int base = blockIdx.x * 2048;   // 512 blocks x 2048 tokens = 1M

#pragma unroll 1
    for (int it = 0; it < 16; ++it) {
        const int t0 = base + it * 128 + wave * 32;   // this wave's 32 tokens
        const int bi = t0 >> 16;
        const int p = t0 & 65535;
        const float* xb = x + bi * 196608 + p;
        const float* yb = y + bi * 196608 + p;

        // ---- Layer 0 (6->32): inputs straight into B-frags; WT0 zero-padded ----
        half8 hb[2];
#pragma unroll
        for (int nt = 0; nt < 2; ++nt) {
            const int tt = nt * 16 + r;
            float c0 = xb[tt], c1 = xb[65536 + tt], c2 = xb[131072 + tt];
            float c3 = yb[tt], c4 = yb[65536 + tt], c5 = yb[131072 + tt];
            half8 h;
#pragma unroll
            for (int e = 0; e < 8; ++e) h[e] = (_Float16)0.f;
            if (g == 0) {   // only k<8 lanes carry real data; A zeros cover the rest
                h[0] = (_Float16)c0; h[1] = (_Float16)c1; h[2] = (_Float16)c2;
                h[3] = (_Float16)c3; h[4] = (_Float16)c4; h[5] = (_Float16)c5;
            }
            hb[nt] = h;
        }
        {
            f32x4 acc[2][2];
#pragma unroll
            for (int m = 0; m < 2; ++m) { acc[m][0] = zero4(); acc[m][1] = zero4(); }
#pragma unroll
            for (int mt = 0; mt < 2; ++mt) {
                half8 a = *(const half8*)(lds + WT0_OFF + (mt * 16 + r) * 80 + g * 16);
                acc[mt][0] = __builtin_amdgcn_mfma_f32_16x16x32_f16(a, hb[0], acc[mt][0], 0, 0, 0);
                acc[mt][1] = __builtin_amdgcn_mfma_f32_16x16x32_f16(a, hb[1], acc[mt][1], 0, 0, 0);
            }
            epilogue<32, true>(lds, B0_OFF, bufA, r, g, acc);
        }
        // ---- Layer 1 (32->128) ----
        {
            f32x4 acc[8][2];
#pragma unroll
            for (int m = 0; m < 8; ++m) { acc[m][0] = zero4(); acc[m][1] = zero4(); }
            gemm_tile<32, 128, 80>(lds + WT1_OFF, bufA, r, g, acc);
            epilogue<128, true>(lds, B1_OFF, bufB, r, g, acc);
        }
        // ---- Layer 2 (128->128) ----
        {
            f32x4 acc[8][2];
#pragma unroll
            for (int m = 0; m < 8; ++m) { acc[m][0] = zero4(); acc[m][1] = zero4(); }
            gemm_tile<128, 128, 272>(lds + WT2_OFF, bufB, r, g, acc);
            epilogue<128, true>(lds, B2_OFF, bufA, r, g, acc);
        }
        // ---- Layer 3 (128->32) ----
        {
            f32x4 acc[2][2];
#pragma unroll
            for (int m = 0; m < 2; ++m) { acc[m][0] = zero4(); acc[m][1] = zero4(); }
            gemm_tile<128, 32, 272>(lds + WT3_OFF, bufA, r, g, acc);
            epilogue<32, true>(lds, B3_OFF, bufB, r, g, acc);
        }
        // ---- Layer 4 (32->16) + Layer 5 (16->1) fused, store ----
        {
            f32x4 acc[1][2];
            acc[0][0] = zero4(); acc[0][1] = zero4();
            gemm_tile<32, 16, 80>(lds + WT4_OFF, bufB, r, g, acc);
            f32x4 b4v = *(const f32x4*)(lds + B4_OFF + g * 16);
            f32x4 w5v = *(const f32x4*)(lds + W5_OFF + g * 16);  // pre-scaled
            float b5v = *(const float*)(lds + B5_OFF);
            float s0, s1;
            {
                float d = 0.f;
#pragma unroll
                for (int e = 0; e < 4; ++e) {
                    float v = acc[0][0][e] + b4v[e];
                    d += act(v) * w5v[e];
                }
                d += __shfl_xor(d, 16);
                d += __shfl_xor(d, 32);
                s0 = d + b5v;
            }
            {
                float d = 0.f;
#pragma unroll
                for (int e = 0; e < 4; ++e) {
                    float v = acc[0][1][e] + b4v[e];
                    d += act(v) * w5v[e];
                }
                d += __shfl_xor(d, 16);
                d += __shfl_xor(d, 32);
                s1 = d + b5v;
            }
            if (lane < 32) out[t0 + lane] = (lane < 16) ? s0 : s1;
        }
    }
}

extern "C" void kernel_launch(void* const* d_in, const int* in_sizes, int n_in,
                              void* d_out, int out_size, void* d_ws, size_t ws_size,
                              hipStream_t stream) {
    const float* x  = (const float*)d_in[0];
    const float* y  = (const float*)d_in[1];
    const float* W0 = (const float*)d_in[2];
    const float* b0 = (const float*)d_in[3];
    const float* W1 = (const float*)d_in[4];
    const float* b1 = (const float*)d_in[5];
    const float* W2 = (const float*)d_in[6];
    const float* b2 = (const float*)d_in[7];
    const float* W3 = (const float*)d_in[8];
    const float* b3 = (const float*)d_in[9];
    const float* W4 = (const float*)d_in[10];
    const float* b4 = (const float*)d_in[11];
    const float* W5 = (const float*)d_in[12];
    const float* b5 = (const float*)d_in[13];
    float* out = (float*)d_out;

    extractor_mlp_kernel<<<dim3(512), dim3(256), 0, stream>>>(
        x, y, W0, b0, W1, b1, W2, b2, W3, b3, W4, b4, W5, b5, out);
}

// Round 4
// 103.601 us; speedup vs baseline: 1.6879x; 1.6879x over previous
//
#include <hip/hip_runtime.h>

typedef _Float16 half8 __attribute__((ext_vector_type(8)));
typedef _Float16 half4 __attribute__((ext_vector_type(4)));
typedef __fp16 fp16x2 __attribute__((ext_vector_type(2)));
typedef float f32x4 __attribute__((ext_vector_type(4)));
typedef unsigned int u32x2 __attribute__((ext_vector_type(2)));

#define SELU_SCALE 1.0507009873554805f
#define SELU_ALPHA 1.6732632423543772f

// ---- LDS layout (bytes) ----
// Weights transposed WT[f_out][k] f16, pitch chosen so (pitch/16)%8 is odd
// => conflict-free b128 A-frag reads (slot analysis, m136/m201 rules).
//   K=32  -> 80 B rows ; K=128 -> 272 B rows
#define WT0_OFF 0        // 32 x 80   (K padded 6->32 with zeros)
#define WT1_OFF 2560     // 128 x 80
#define WT2_OFF 12800    // 128 x 272
#define WT3_OFF 47616    // 32 x 272
#define WT4_OFF 56320    // 16 x 80
#define B0_OFF  57600
#define B1_OFF  57728
#define B2_OFF  58240
#define B3_OFF  58752
#define B4_OFF  58880
#define W5_OFF  58944    // 16 f32 (pre-scaled)
#define B5_OFF  59008
#define ACT_OFF 59024    // 8 waves x (32 rows x 272 B) single buffer each
#define BUF_SZ  8704
#define LDS_SZ  (ACT_OFF + 8 * BUF_SZ)   // 128656 B -> 1 block/CU, 8 waves = 2/SIMD

__device__ __forceinline__ unsigned short f2h(float f) {
    union { _Float16 h; unsigned short u; } v;
    v.h = (_Float16)f;
    return v.u;
}

// SELU minus the global scale (folded into consumer weights):
// act(x) = x>0 ? x : alpha*exp(x) - alpha   (mul,exp,fma,cmp,cndmask = 5 ops)
__device__ __forceinline__ float act(float x) {
    float y = __builtin_fmaf(SELU_ALPHA, __expf(x), -SELU_ALPHA);
    return x > 0.0f ? x : y;
}

__device__ __forceinline__ unsigned pk2(float a, float b) {
    union { fp16x2 h; unsigned u; } v;
    v.h = __builtin_amdgcn_cvt_pkrtz(a, b);
    return v.u;
}

// act + pack 4 accumulator floats -> half4 (feeds 16x16x16 B-frag directly:
// D-frag row=(lane>>4)*4+e  ==  x16 B-frag k=(lane>>4)*4+e)
__device__ __forceinline__ half4 pack4(f32x4 a) {
    union { unsigned u[2]; half4 h; } w;
    w.u[0] = pk2(act(a[0]), act(a[1]));
    w.u[1] = pk2(act(a[2]), act(a[3]));
    return w.h;
}

// ---- LDS B-frag loads (x32 layout): token=nt*16+r, k=kk*32+g*8+e ----
template<int KIN>
__device__ __forceinline__ void load_b(const unsigned char* buf, int r, int g,
                                       half8 (&b)[2][KIN / 32]) {
    asm volatile("" ::: "memory");   // order vs prior same-buffer stores
#pragma unroll
    for (int nt = 0; nt < 2; ++nt)
#pragma unroll
        for (int kk = 0; kk < KIN / 32; ++kk)
            b[nt][kk] = *(const half8*)(buf + (nt * 16 + r) * 272 + kk * 64 + g * 16);
}

// ---- MFMA over LDS-resident A (x32) ----
template<int KIN, int FOUT, int WRP>
__device__ __forceinline__ void gemm_lds(const unsigned char* wt, int r, int g,
                                         half8 (&b)[2][KIN / 32],
                                         f32x4 (&acc)[FOUT / 16][2]) {
#pragma unroll
    for (int kk = 0; kk < KIN / 32; ++kk)
#pragma unroll
        for (int mt = 0; mt < FOUT / 16; ++mt) {
            half8 a = *(const half8*)(wt + (mt * 16 + r) * WRP + kk * 64 + g * 16);
            acc[mt][0] = __builtin_amdgcn_mfma_f32_16x16x32_f16(a, b[0][kk], acc[mt][0], 0, 0, 0);
            acc[mt][1] = __builtin_amdgcn_mfma_f32_16x16x32_f16(a, b[1][kk], acc[mt][1], 0, 0, 0);
        }
}

// ---- acc init = bias (replaces zero-init, deletes the bias v_adds) ----
template<int FOUT>
__device__ __forceinline__ void init_acc(const unsigned char* lds, int off, int g,
                                         f32x4 (&acc)[FOUT / 16][2]) {
#pragma unroll
    for (int mt = 0; mt < FOUT / 16; ++mt) {
        f32x4 bv = *(const f32x4*)(lds + off + (mt * 16 + g * 4) * 4);
        acc[mt][0] = bv;
        acc[mt][1] = bv;
    }
}

// ---- act + pack + store to LDS act buffer ----
template<int FOUT>
__device__ __forceinline__ void epi_store(unsigned char* dst, int r, int g,
                                          f32x4 (&acc)[FOUT / 16][2]) {
    asm volatile("" ::: "memory");   // order vs prior same-buffer reads
#pragma unroll
    for (int mt = 0; mt < FOUT / 16; ++mt)
#pragma unroll
        for (int nt = 0; nt < 2; ++nt) {
            u32x2 w;
            w[0] = pk2(act(acc[mt][nt][0]), act(acc[mt][nt][1]));
            w[1] = pk2(act(acc[mt][nt][2]), act(acc[mt][nt][3]));
            *(u32x2*)(dst + (nt * 16 + r) * 272 + (mt * 16 + g * 4) * 2) = w;
        }
}

__device__ __forceinline__ void load_inputs(const float* __restrict__ x,
                                            const float* __restrict__ y,
                                            int t0, int r, float (&c)[12]) {
    const int bi = t0 >> 16;
    const int p = t0 & 65535;
    const float* xb = x + bi * 196608 + p;
    const float* yb = y + bi * 196608 + p;
#pragma unroll
    for (int nt = 0; nt < 2; ++nt) {
        const int tt = nt * 16 + r;
        c[nt * 6 + 0] = xb[tt];
        c[nt * 6 + 1] = xb[65536 + tt];
        c[nt * 6 + 2] = xb[131072 + tt];
        c[nt * 6 + 3] = yb[tt];
        c[nt * 6 + 4] = yb[65536 + tt];
        c[nt * 6 + 5] = yb[131072 + tt];
    }
}

extern "C" __global__ void __launch_bounds__(512, 2)
extractor_mlp_kernel(const float* __restrict__ x, const float* __restrict__ y,
                     const float* __restrict__ W0, const float* __restrict__ b0,
                     const float* __restrict__ W1, const float* __restrict__ b1,
                     const float* __restrict__ W2, const float* __restrict__ b2,
                     const float* __restrict__ W3, const float* __restrict__ b3,
                     const float* __restrict__ W4, const float* __restrict__ b4,
                     const float* __restrict__ W5, const float* __restrict__ b5,
                     float* __restrict__ out) {
    __shared__ __align__(16) unsigned char lds[LDS_SZ];
    const int tid = threadIdx.x;

    // ---------- stage weights (f16, transposed, scale-folded) ----------
    for (int i = tid; i < 32 * 40; i += 512) {
        int f = i / 40, c = i % 40;
        float v = (c < 6) ? W0[c * 32 + f] : 0.0f;
        ((unsigned short*)(lds + WT0_OFF))[f * 40 + c] = f2h(v);
    }
    for (int i = tid; i < 32 * 128; i += 512) {
        int k = i >> 7, f = i & 127;
        ((unsigned short*)(lds + WT1_OFF))[f * 40 + k] = f2h(W1[i] * SELU_SCALE);
    }
    for (int i = tid; i < 128 * 128; i += 512) {
        int k = i >> 7, f = i & 127;
        ((unsigned short*)(lds + WT2_OFF))[f * 136 + k] = f2h(W2[i] * SELU_SCALE);
    }
    for (int i = tid; i < 128 * 32; i += 512) {
        int k = i >> 5, f = i & 31;
        ((unsigned short*)(lds + WT3_OFF))[f * 136 + k] = f2h(W3[i] * SELU_SCALE);
    }
    for (int i = tid; i < 32 * 16; i += 512) {
        int k = i >> 4, f = i & 15;
        ((unsigned short*)(lds + WT4_OFF))[f * 40 + k] = f2h(W4[i] * SELU_SCALE);
    }
    for (int i = tid; i < 32; i += 512)  ((float*)(lds + B0_OFF))[i] = b0[i];
    for (int i = tid; i < 128; i += 512) ((float*)(lds + B1_OFF))[i] = b1[i];
    for (int i = tid; i < 128; i += 512) ((float*)(lds + B2_OFF))[i] = b2[i];
    for (int i = tid; i < 32; i += 512)  ((float*)(lds + B3_OFF))[i] = b3[i];
    for (int i = tid; i < 16; i += 512)  ((float*)(lds + B4_OFF))[i] = b4[i];
    for (int i = tid; i < 16; i += 512)  ((float*)(lds + W5_OFF))[i] = W5[i] * SELU_SCALE;
    if (tid == 0) *(float*)(lds + B5_OFF) = b5[0];
    __syncthreads();   // only block-wide barrier

    const int lane = tid & 63;
    const int wave = tid >> 6;
    const int r = lane & 15;
    const int g = lane >> 4;
    unsigned char* buf = lds + ACT_OFF + wave * BUF_SZ;

    // ---------- hoist loop-invariant fragments into registers ----------
    half8 wa0[2];      // L0 A (x32)
    half4 wa1[8][2];   // L1 A (x16): [mt][kt]
    half4 wa4[2];      // L4 A (x16): [kt]
    f32x4 bv0[2], bv3[2];
#pragma unroll
    for (int mt = 0; mt < 2; ++mt) {
        wa0[mt] = *(const half8*)(lds + WT0_OFF + (mt * 16 + r) * 80 + g * 16);
        bv0[mt] = *(const f32x4*)(lds + B0_OFF + (mt * 16 + g * 4) * 4);
        bv3[mt] = *(const f32x4*)(lds + B3_OFF + (mt * 16 + g * 4) * 4);
    }
#pragma unroll
    for (int mt = 0; mt < 8; ++mt)
#pragma unroll
        for (int kt = 0; kt < 2; ++kt)
            wa1[mt][kt] = *(const half4*)(lds + WT1_OFF + (mt * 16 + r) * 80 + kt * 32 + g * 8);
#pragma unroll
    for (int kt = 0; kt < 2; ++kt)
        wa4[kt] = *(const half4*)(lds + WT4_OFF + r * 80 + kt * 32 + g * 8);
    const f32x4 b4v = *(const f32x4*)(lds + B4_OFF + g * 16);
    const f32x4 w5v = *(const f32x4*)(lds + W5_OFF + g * 16);
    const float b5v = *(const float*)(lds + B5_OFF);

    const int base = blockIdx.x * 4096;   // 256 blocks x 4096 tokens = 1M
    float cur[12], nxt[12];
    load_inputs(x, y, base + wave * 32, r, cur);

#pragma unroll 1
    for (int it = 0; it < 16; ++it) {
        const int t0 = base + it * 256 + wave * 32;

        // ---- L0 (6->32, x32): inputs in regs, WT0 zero-padded ----
        f32x4 a0[2][2];
#pragma unroll
        for (int mt = 0; mt < 2; ++mt) { a0[mt][0] = bv0[mt]; a0[mt][1] = bv0[mt]; }
        {
            half8 hb[2];
#pragma unroll
            for (int nt = 0; nt < 2; ++nt) {
                half8 h;
#pragma unroll
                for (int e = 0; e < 8; ++e) h[e] = (_Float16)0.f;
                if (g == 0) {
#pragma unroll
                    for (int e = 0; e < 6; ++e) h[e] = (_Float16)cur[nt * 6 + e];
                }
                hb[nt] = h;
            }
#pragma unroll
            for (int mt = 0; mt < 2; ++mt) {
                a0[mt][0] = __builtin_amdgcn_mfma_f32_16x16x32_f16(wa0[mt], hb[0], a0[mt][0], 0, 0, 0);
                a0[mt][1] = __builtin_amdgcn_mfma_f32_16x16x32_f16(wa0[mt], hb[1], a0[mt][1], 0, 0, 0);
            }
        }

        // ---- L1 (32->128, x16): B comes straight from a0 in registers ----
        f32x4 a1[8][2];
        init_acc<128>(lds, B1_OFF, g, a1);
        {
            half4 p[2][2];   // [kt][nt]
#pragma unroll
            for (int kt = 0; kt < 2; ++kt)
#pragma unroll
                for (int nt = 0; nt < 2; ++nt) p[kt][nt] = pack4(a0[kt][nt]);
#pragma unroll
            for (int kt = 0; kt < 2; ++kt)
#pragma unroll
                for (int mt = 0; mt < 8; ++mt) {
                    a1[mt][0] = __builtin_amdgcn_mfma_f32_16x16x16f16(wa1[mt][kt], p[kt][0], a1[mt][0], 0, 0, 0);
                    a1[mt][1] = __builtin_amdgcn_mfma_f32_16x16x16f16(wa1[mt][kt], p[kt][1], a1[mt][1], 0, 0, 0);
                }
        }
        epi_store<128>(buf, r, g, a1);

        // prefetch next iteration's inputs under the L2 MFMA phase
        if (it != 15) load_inputs(x, y, t0 + 256, r, nxt);

        // ---- L2 (128->128, x32) through LDS ----
        {
            half8 b2f[2][4];
            load_b<128>(buf, r, g, b2f);
            f32x4 a2[8][2];
            init_acc<128>(lds, B2_OFF, g, a2);
            gemm_lds<128, 128, 272>(lds + WT2_OFF, r, g, b2f, a2);
            epi_store<128>(buf, r, g, a2);
        }

        // ---- L3 (128->32, x32) + L4 (32->16, x16, reg-fed) + L5 dot ----
        {
            half8 b3f[2][4];
            load_b<128>(buf, r, g, b3f);
            f32x4 a3[2][2];
#pragma unroll
            for (int mt = 0; mt < 2; ++mt) { a3[mt][0] = bv3[mt]; a3[mt][1] = bv3[mt]; }
            gemm_lds<128, 32, 272>(lds + WT3_OFF, r, g, b3f, a3);

            f32x4 a4[2];
            a4[0] = b4v; a4[1] = b4v;
#pragma unroll
            for (int kt = 0; kt < 2; ++kt) {
                half4 p0 = pack4(a3[kt][0]);
                half4 p1 = pack4(a3[kt][1]);
                a4[0] = __builtin_amdgcn_mfma_f32_16x16x16f16(wa4[kt], p0, a4[0], 0, 0, 0);
                a4[1] = __builtin_amdgcn_mfma_f32_16x16x16f16(wa4[kt], p1, a4[1], 0, 0, 0);
            }

            float s[2];
#pragma unroll
            for (int nt = 0; nt < 2; ++nt) {
                float d = 0.f;
#pragma unroll
                for (int e = 0; e < 4; ++e) d += act(a4[nt][e]) * w5v[e];
                d += __shfl_xor(d, 16);
                d += __shfl_xor(d, 32);
                s[nt] = d + b5v;
            }
            if (lane < 32) out[t0 + lane] = (lane < 16) ? s[0] : s[1];
        }

#pragma unroll
        for (int i = 0; i < 12; ++i) cur[i] = nxt[i];
    }
}

extern "C" void kernel_launch(void* const* d_in, const int* in_sizes, int n_in,
                              void* d_out, int out_size, void* d_ws, size_t ws_size,
                              hipStream_t stream) {
    const float* x  = (const float*)d_in[0];
    const float* y  = (const float*)d_in[1];
    const float* W0 = (const float*)d_in[2];
    const float* b0 = (const float*)d_in[3];
    const float* W1 = (const float*)d_in[4];
    const float* b1 = (const float*)d_in[5];
    const float* W2 = (const float*)d_in[6];
    const float* b2 = (const float*)d_in[7];
    const float* W3 = (const float*)d_in[8];
    const float* b3 = (const float*)d_in[9];
    const float* W4 = (const float*)d_in[10];
    const float* b4 = (const float*)d_in[11];
    const float* W5 = (const float*)d_in[12];
    const float* b5 = (const float*)d_in[13];
    float* out = (float*)d_out;

    extractor_mlp_kernel<<<dim3(256), dim3(512), 0, stream>>>(
        x, y, W0, b0, W1, b1, W2, b2, W3, b3, W4, b4, W5, b5, out);
}